// Round 5
// baseline (496.988 us; speedup 1.0000x reference)
//
#include <hip/hip_runtime.h>
#include <hip/hip_bf16.h>
#include <stdint.h>

#define BDIM 1024
#define SDIM 256
#define VDIM 32000
#define EDIM 300
#define HDIM 256
#define ENCD 768
#define G4H  1024
#define KXI  1344   // 300 + 768 + 256 = 1324 padded to 42*32

typedef short bf16x8 __attribute__((ext_vector_type(8)));
typedef float f32x4  __attribute__((ext_vector_type(4)));

typedef __attribute__((address_space(3))) void       lds_void;
typedef const __attribute__((address_space(1))) void gbl_void;

static __device__ __forceinline__ unsigned short f2bf(float f) {
  __hip_bfloat16 b = __float2bfloat16(f);   // RNE
  return *reinterpret_cast<unsigned short*>(&b);
}
static __device__ __forceinline__ unsigned pk2(float x, float y) {
  float2 f; f.x = x; f.y = y;
  __hip_bfloat162 h = __float22bfloat162_rn(f);   // packed RNE (v_cvt_pk_bf16_f32)
  return *reinterpret_cast<unsigned*>(&h);
}
static __device__ __forceinline__ float sigf(float x) {
  return 1.0f / (1.0f + __expf(-x));
}
static __device__ __forceinline__ float tanh_fast(float x) {
  return 1.0f - 2.0f / (__expf(2.0f * x) + 1.0f);   // saturates correctly at +-inf
}

// ---------------- prep: bf16 conversions + w_h transpose ----------------
__global__ void k_prep(const float* __restrict__ attn_w, const float* __restrict__ w_ih,
                       const float* __restrict__ w_hh, const float* __restrict__ out_w,
                       unsigned short* __restrict__ w_e_b, float* __restrict__ w_hT,
                       unsigned short* __restrict__ Wb, unsigned short* __restrict__ outw_b) {
  const long NWE = (long)HDIM * ENCD;       // 196608
  const long NWH = (long)HDIM * HDIM;       // 65536
  const long NWB = (long)G4H * KXI;         // 1376256
  const long NOW = (long)VDIM * HDIM;       // 8192000
  const long total = NWE + NWH + NWB + NOW;
  for (long idx = blockIdx.x * 256L + threadIdx.x; idx < total; idx += gridDim.x * 256L) {
    long i = idx;
    if (i < NWE) {
      int j = (int)(i / ENCD), d = (int)(i % ENCD);
      w_e_b[i] = f2bf(attn_w[j * (4 * HDIM) + HDIM + d]);
    } else if ((i -= NWE) < NWH) {
      int k = (int)(i / HDIM), j = (int)(i % HDIM);
      w_hT[i] = attn_w[j * (4 * HDIM) + k];
    } else if ((i -= NWH) < NWB) {
      int g = (int)(i / KXI), k = (int)(i % KXI);
      float v = 0.f;
      if (k < EDIM + ENCD) v = w_ih[(long)g * (EDIM + ENCD) + k];
      else if (k < EDIM + ENCD + HDIM) v = w_hh[(long)g * HDIM + (k - (EDIM + ENCD))];
      Wb[i] = f2bf(v);
    } else {
      i -= NWB;
      outw_b[i] = f2bf(out_w[i]);
    }
  }
}

// ---------------- hwb[b][j] = h[b] . w_h[j] + attn_b[j] ----------------
__global__ void k_hwb(const float* __restrict__ h, const float* __restrict__ w_hT,
                      const float* __restrict__ attn_b, float* __restrict__ hwb) {
  int b = blockIdx.x, t = threadIdx.x;
  __shared__ float hl[HDIM];
  hl[t] = h[b * HDIM + t];
  __syncthreads();
  float acc = attn_b[t];
#pragma unroll 8
  for (int k = 0; k < HDIM; ++k) acc += hl[k] * w_hT[k * HDIM + t];
  hwb[b * HDIM + t] = acc;
}

// ---------------- fused per-b: 256x256x768 energy GEMM + tanh/score + softmax + context + xi ----------------
// One WG per b. m201 geometry: 8 waves (2M x 4N), wave tile 128s x 64j, BK=64,
// 12 K-steps, double-buffered 128KB LDS. B via global_load_lds (XOR-preswizzled
// source); A reg-staged (fp32->bf16). Full j-reduction + softmax + context in-block.
__launch_bounds__(512, 2)
__global__ void k_score_ctx(const float* __restrict__ enc, const unsigned short* __restrict__ w_e_b,
                            const float* __restrict__ hwb, const float* __restrict__ v_w,
                            const int* __restrict__ x, const float* __restrict__ emb,
                            const float* __restrict__ h, unsigned short* __restrict__ xi_b) {
  const int b = blockIdx.x;
  const int t = threadIdx.x;
  const int lane = t & 63;
  const int w = t >> 6;           // wave 0..7
  const int li = lane & 15, lg = lane >> 4;
  const int wm = w >> 2, wn = w & 3;   // wave tile: s in [wm*128,+128), j in [wn*64,+64)

  __shared__ __align__(16) char smem[131072];
  // A bufs (enc bf16, 256x64, row stride 128B, chunk-XOR swizzled): 2 x 32KB
  // B bufs (w_e bf16, 256x64, same layout): 2 x 32KB
  float* scores_part = (float*)smem;            // 4KB overlay (A0 dead after K-loop)
  float* p_lds       = (float*)(smem + 4096);   // 1KB
  float* dpart       = (float*)(smem + 5120);   // 16B

  const float* encB = enc + (long)b * SDIM * ENCD;

  // A staging: thread t covers row rA = t>>1, cols [(t&1)*32, +32) => 8 float4
  const int rA  = t >> 1;
  const int cA0 = (t & 1) * 32;
  const float* srcA = encB + (long)rA * ENCD + cA0;
  float4 sv[8];

  // B staging: per q-block of 64 j: slot = q*512 + t; j = q*64 + (t>>3);
  // stored chunk (t&7) holds source chunk (t&7)^(j&7)  [XOR pre-swizzle]
  const int jB  = t >> 3;
  const int kcB = (t & 7) ^ (jB & 7);

  f32x4 acc[8][4];
#pragma unroll
  for (int m = 0; m < 8; m++)
#pragma unroll
    for (int n = 0; n < 4; n++) { f32x4 z = {0.f, 0.f, 0.f, 0.f}; acc[m][n] = z; }

  // ---------- prologue: stage k-tile 0 ----------
#pragma unroll
  for (int i = 0; i < 8; ++i) sv[i] = *(const float4*)(srcA + i * 4);
#pragma unroll
  for (int q = 0; q < 4; ++q) {
    const unsigned short* src = w_e_b + (long)(q * 64 + jB) * ENCD + kcB * 8;
    char* dst = smem + 65536 + (q * 512 + w * 64) * 16;
    __builtin_amdgcn_global_load_lds((gbl_void*)src, (lds_void*)dst, 16, 0, 0);
  }
#pragma unroll
  for (int i = 0; i < 4; ++i) {
    uint4 pk;
    pk.x = pk2(sv[2*i].x, sv[2*i].y);     pk.y = pk2(sv[2*i].z, sv[2*i].w);
    pk.z = pk2(sv[2*i+1].x, sv[2*i+1].y); pk.w = pk2(sv[2*i+1].z, sv[2*i+1].w);
    const int kc = (t & 1) * 4 + i;
    *(uint4*)(smem + rA * 128 + ((kc ^ (rA & 7)) * 16)) = pk;
  }
  __syncthreads();   // full drain: A0 written, B0 landed (vmcnt 0 via syncthreads semantics)

  // epilogue operands (hide under loop)
  float hw[4], vw[4];
#pragma unroll
  for (int n = 0; n < 4; ++n) {
    int j = wn * 64 + n * 16 + li;
    hw[n] = hwb[b * HDIM + j];
    vw[n] = v_w[j];
  }

  // ---------- K-loop: 12 steps, 64 MFMA/wave/step ----------
#pragma unroll
  for (int kt = 0; kt < 12; ++kt) {
    char* Ac = smem + (kt & 1) * 32768;
    char* Bc = smem + 65536 + (kt & 1) * 32768;
    char* An = smem + ((kt + 1) & 1) * 32768;
    char* Bn = smem + 65536 + ((kt + 1) & 1) * 32768;
    const bool more = (kt + 1 < 12);
    if (more) {
      const int k0 = (kt + 1) * 64;
#pragma unroll
      for (int i = 0; i < 8; ++i) sv[i] = *(const float4*)(srcA + k0 + i * 4);
#pragma unroll
      for (int q = 0; q < 4; ++q) {
        const unsigned short* src = w_e_b + (long)(q * 64 + jB) * ENCD + k0 + kcB * 8;
        char* dst = Bn + (q * 512 + w * 64) * 16;
        __builtin_amdgcn_global_load_lds((gbl_void*)src, (lds_void*)dst, 16, 0, 0);
      }
    }
    // compute current tile
#pragma unroll
    for (int ks = 0; ks < 2; ++ks) {
      bf16x8 bfr[4];
#pragma unroll
      for (int n = 0; n < 4; ++n) {
        const int j = wn * 64 + n * 16 + li;
        bfr[n] = *(const bf16x8*)(Bc + j * 128 + (((ks * 4 + lg) ^ (j & 7)) * 16));
      }
#pragma unroll
      for (int m = 0; m < 8; ++m) {
        const int s = wm * 128 + m * 16 + li;
        bf16x8 af = *(const bf16x8*)(Ac + s * 128 + (((ks * 4 + lg) ^ (s & 7)) * 16));
#pragma unroll
        for (int n = 0; n < 4; ++n)
          acc[m][n] = __builtin_amdgcn_mfma_f32_16x16x32_bf16(af, bfr[n], acc[m][n], 0, 0, 0);
      }
    }
    if (more) {
      // compiler inserts vmcnt wait for sv here; write A(kt+1)
#pragma unroll
      for (int i = 0; i < 4; ++i) {
        uint4 pk;
        pk.x = pk2(sv[2*i].x, sv[2*i].y);     pk.y = pk2(sv[2*i].z, sv[2*i].w);
        pk.z = pk2(sv[2*i+1].x, sv[2*i+1].y); pk.w = pk2(sv[2*i+1].z, sv[2*i+1].w);
        const int kc = (t & 1) * 4 + i;
        *(uint4*)(An + rA * 128 + ((kc ^ (rA & 7)) * 16)) = pk;
      }
      __syncthreads();  // drains vmcnt(0)+lgkmcnt(0): B(kt+1) landed, A(kt+1) visible
    }
  }

  // ---------- epilogue: tanh -> *v_w -> j-reduce -> scores ----------
#pragma unroll
  for (int m = 0; m < 8; ++m)
#pragma unroll
    for (int r = 0; r < 4; ++r) {
      float v0 = 0.f;
#pragma unroll
      for (int n = 0; n < 4; ++n) v0 += tanh_fast(acc[m][n][r] + hw[n]) * vw[n];
      v0 += __shfl_xor(v0, 1);
      v0 += __shfl_xor(v0, 2);
      v0 += __shfl_xor(v0, 4);
      v0 += __shfl_xor(v0, 8);
      if (li == 0) scores_part[wn * 256 + wm * 128 + m * 16 + lg * 4 + r] = v0;
    }
  __syncthreads();

  // softmax over s (unnormalized exp is safe: |score| <= sum|v_w|)
  if (t < 256) {
    float sc = scores_part[t] + scores_part[256 + t] + scores_part[512 + t] + scores_part[768 + t];
    float p = __expf(sc);
    p_lds[t] = p;
    float d = p;
    d += __shfl_xor(d, 1);
    d += __shfl_xor(d, 2);
    d += __shfl_xor(d, 4);
    d += __shfl_xor(d, 8);
    d += __shfl_xor(d, 16);
    d += __shfl_xor(d, 32);
    if (lane == 0) dpart[w] = d;
  }
  __syncthreads();
  const float inv = 1.0f / (dpart[0] + dpart[1] + dpart[2] + dpart[3]);

  // ---------- context (enc re-read, L3-warm) + xi assembly ----------
  if (t < 384) {
    float cx = 0.f, cy = 0.f;
    const float* ep = encB + 2 * t;
#pragma unroll 8
    for (int s = 0; s < 256; ++s) {
      float2 e2 = *(const float2*)(ep + (long)s * ENCD);
      float p = p_lds[s];
      cx += p * e2.x;
      cy += p * e2.y;
    }
    xi_b[(long)b * KXI + EDIM + 2 * t]     = f2bf(cx * inv);
    xi_b[(long)b * KXI + EDIM + 2 * t + 1] = f2bf(cy * inv);
  }
  const int xv = x[b];
  for (int cc = t; cc < EDIM; cc += 512)
    xi_b[(long)b * KXI + cc] = f2bf(emb[(long)xv * EDIM + cc]);
  if (t < HDIM)
    xi_b[(long)b * KXI + EDIM + ENCD + t] = f2bf(h[b * HDIM + t]);
  if (t >= HDIM && t < HDIM + (KXI - (EDIM + ENCD + HDIM)))
    xi_b[(long)b * KXI + EDIM + ENCD + HDIM + (t - HDIM)] = 0;
}

// ---------------- generic 128x128 bf16 GEMM, C = A * Bt^T + bias ----------------
__launch_bounds__(256)
__global__ void k_gemm_bt(const unsigned short* __restrict__ A, const unsigned short* __restrict__ Bt,
                          const float* __restrict__ bias1, const float* __restrict__ bias2,
                          float* __restrict__ out, int N, int K, int MTILES) {
  int bx = blockIdx.x;
  int mt = bx % MTILES, nt = bx / MTILES;
  int row0 = mt * 128, col0 = nt * 128;
  int t = threadIdx.x, lane = t & 63, w = t >> 6;
  int li = lane & 15, lg = lane >> 4;
  int wr = (w >> 1) * 64, wc = (w & 1) * 64;
  __shared__ __align__(16) unsigned short As[2][128 * 32];
  __shared__ __align__(16) unsigned short Bs[2][128 * 32];
  f32x4 acc[4][4];
#pragma unroll
  for (int m = 0; m < 4; m++)
#pragma unroll
    for (int n = 0; n < 4; n++) { f32x4 z = {0.f, 0.f, 0.f, 0.f}; acc[m][n] = z; }

  auto stage = [&](int buf, int k0) {
#pragma unroll
    for (int rep = 0; rep < 2; ++rep) {
      int slot = t + rep * 256;
      int r = slot >> 2, sg = slot & 3;
      uint4 va = *(const uint4*)(A + (long)(row0 + r) * K + k0 + sg * 8);
      uint4 vb = *(const uint4*)(Bt + (long)(col0 + r) * K + k0 + sg * 8);
      *(uint4*)&As[buf][r * 32 + sg * 8] = va;
      *(uint4*)&Bs[buf][r * 32 + sg * 8] = vb;
    }
  };

  stage(0, 0);
  __syncthreads();
  const int nk = K / 32;
  for (int kt = 0; kt < nk; ++kt) {
    if (kt + 1 < nk) stage((kt + 1) & 1, (kt + 1) * 32);
    int cb = kt & 1;
    bf16x8 a[4], bb[4];
#pragma unroll
    for (int m = 0; m < 4; m++) a[m] = *(const bf16x8*)&As[cb][(wr + 16 * m + li) * 32 + lg * 8];
#pragma unroll
    for (int n = 0; n < 4; n++) bb[n] = *(const bf16x8*)&Bs[cb][(wc + 16 * n + li) * 32 + lg * 8];
#pragma unroll
    for (int m = 0; m < 4; m++)
#pragma unroll
      for (int n = 0; n < 4; n++)
        acc[m][n] = __builtin_amdgcn_mfma_f32_16x16x32_bf16(a[m], bb[n], acc[m][n], 0, 0, 0);
    __syncthreads();
  }

#pragma unroll
  for (int n = 0; n < 4; n++) {
    int col = col0 + wc + 16 * n + li;
    float bs = bias1[col];
    if (bias2) bs += bias2[col];
#pragma unroll
    for (int m = 0; m < 4; m++) {
      int rb = row0 + wr + 16 * m + lg * 4;
#pragma unroll
      for (int r = 0; r < 4; r++)
        out[(long)(rb + r) * N + col] = acc[m][n][r] + bs;
    }
  }
}

// ---------------- LSTM pointwise ----------------
__global__ void k_lstm(const float* __restrict__ gates, const float* __restrict__ c,
                       float* __restrict__ h2, float* __restrict__ c2,
                       unsigned short* __restrict__ h2b) {
  int b = blockIdx.x, j = threadIdx.x;
  const float* g = gates + (long)b * G4H;
  float ig = sigf(g[j]);
  float fg = sigf(g[HDIM + j]);
  float gg = tanh_fast(g[2 * HDIM + j]);
  float og = sigf(g[3 * HDIM + j]);
  float cv = c[b * HDIM + j];
  float c2v = fg * cv + ig * gg;
  float h2v = og * tanh_fast(c2v);
  c2[b * HDIM + j] = c2v;
  h2[b * HDIM + j] = h2v;
  h2b[b * HDIM + j] = f2bf(h2v);
}

extern "C" void kernel_launch(void* const* d_in, const int* in_sizes, int n_in,
                              void* d_out, int out_size, void* d_ws, size_t ws_size,
                              hipStream_t stream) {
  const int*   x      = (const int*)d_in[0];
  const float* h      = (const float*)d_in[1];
  const float* c      = (const float*)d_in[2];
  const float* enc    = (const float*)d_in[3];
  const float* emb    = (const float*)d_in[4];
  const float* attn_w = (const float*)d_in[5];
  const float* attn_b = (const float*)d_in[6];
  const float* v_w    = (const float*)d_in[7];
  const float* w_ih   = (const float*)d_in[8];
  const float* w_hh   = (const float*)d_in[9];
  const float* b_ih   = (const float*)d_in[10];
  const float* b_hh   = (const float*)d_in[11];
  const float* out_w  = (const float*)d_in[12];
  const float* out_b  = (const float*)d_in[13];
  float* out = (float*)d_out;

  // workspace layout (bytes)
  char* ws = (char*)d_ws;
  float* hwb            = (float*)(ws + 0);                 // 1,048,576
  unsigned short* w_e_b = (unsigned short*)(ws + 1048576);  //   393,216
  float* w_hT           = (float*)(ws + 1441792);           //   262,144
  unsigned short* Wb    = (unsigned short*)(ws + 1703936);  // 2,752,512
  unsigned short* xi_b  = (unsigned short*)(ws + 4456448);  // 2,752,512
  float* gates          = (float*)(ws + 7208960);           // 4,194,304
  unsigned short* h2b   = (unsigned short*)(ws + 11403264); //   524,288
  unsigned short* outw_b= (unsigned short*)(ws + 11927552); // 16,384,000 -> end 28,311,552
  if (ws_size < 28311552u) return;

  k_prep<<<2048, 256, 0, stream>>>(attn_w, w_ih, w_hh, out_w, w_e_b, w_hT, Wb, outw_b);
  k_hwb<<<1024, 256, 0, stream>>>(h, w_hT, attn_b, hwb);
  k_score_ctx<<<1024, 512, 0, stream>>>(enc, w_e_b, hwb, v_w, x, emb, h, xi_b);
  k_gemm_bt<<<64, 256, 0, stream>>>(xi_b, Wb, b_ih, b_hh, gates, G4H, KXI, 8);
  k_lstm<<<1024, 256, 0, stream>>>(gates, c, out + (long)BDIM * VDIM,
                                   out + (long)BDIM * VDIM + (long)BDIM * HDIM, h2b);
  k_gemm_bt<<<2000, 256, 0, stream>>>(h2b, outw_b, out_b, nullptr, out, VDIM, HDIM, 8);
}